// Round 4
// baseline (3750.605 us; speedup 1.0000x reference)
//
#include <hip/hip_runtime.h>
#include <hip/hip_bf16.h>
#include <cmath>
#include <complex>
#include <vector>
#include <cstring>
#include <cstdint>

// ---------------------------------------------------------------------------
// ShieldingT2Model: f32 implementation, round 4.
// B=16384, NS=64, NK=32, NL=16, HM=256, HC=128, out = (B,5) f32.
//
// Round-3 post-mortem: fused k_main was latency-bound (VALUBusy 15%,
// occupancy 24% = 1 block/CU due to 143 KB LDS). This round splits it:
//   k_y   : builds y0 (B x 128) + y2 (B x 5 x 128) into ws. ~39 KB LDS,
//           4 blocks/CU, flat-loop y000 with unroll-8 for load pipelining.
//   k_tp2 : quadratic tp2 contractions + epilogue. ~51 KB LDS, 3 blocks/CU.
// Fallback to the round-3 fused k_main if ws_size < ~52 MB.
//
// ws layout (split path, ~49.4 MB):
//   mixed  @ 0        : B*5 f32      (327680)
//   w202T  @ 327680   : 128*128 f32  (65536)
//   wsym   @ 393216   : 2080*128 f32 (1064960)
//   y0     @ 1458176  : B*128 f32    (8388608)
//   y2     @ 9846784  : B*5*128 f32  (41943040)
// C222 sign: majority-positive canonicalization, then flipped (round-2 A/B
// established the reference's fp-noise argmax picked the minority branch).
// ---------------------------------------------------------------------------

#define C222_FLIP -1.0f

#define MIX_WS_OFF   0
#define W202T_OFF    327680
#define WSYM_OFF     393216
#define Y0_WS_OFF    1458176
#define Y2_WS_OFF    9846784
#define WS_NEEDED    51789824ULL

struct Coefs {
  float c222[125];   // full (2,2,2) real wigner-3j, [i][j][k]
  float d022[5];     // diag of C022[0,:,:]
  float d202[5];     // diag of C202[:,0,:]
  float d220[5];     // diag of C220[:,:,0]
  float a0, a2, b2;
};

#define FMA8(acc, wa, wb, sv) do { \
  acc[0] = fmaf((wa).x, (sv), acc[0]); \
  acc[1] = fmaf((wa).y, (sv), acc[1]); \
  acc[2] = fmaf((wa).z, (sv), acc[2]); \
  acc[3] = fmaf((wa).w, (sv), acc[3]); \
  acc[4] = fmaf((wb).x, (sv), acc[4]); \
  acc[5] = fmaf((wb).y, (sv), acc[5]); \
  acc[6] = fmaf((wb).z, (sv), acc[6]); \
  acc[7] = fmaf((wb).w, (sv), acc[7]); \
} while (0)

#define FMA4(acc, wa, sv) do { \
  acc[0] = fmaf((wa).x, (sv), acc[0]); \
  acc[1] = fmaf((wa).y, (sv), acc[1]); \
  acc[2] = fmaf((wa).z, (sv), acc[2]); \
  acc[3] = fmaf((wa).w, (sv), acc[3]); \
} while (0)

__device__ __forceinline__ float act_silu(float x) {
  return 1.679f * x / (1.0f + expf(-x));   // SILU_NORM * silu(x)
}

__device__ __forceinline__ float waveReduce64(float v) {
  v += __shfl_xor(v, 32);
  v += __shfl_xor(v, 16);
  v += __shfl_xor(v, 8);
  v += __shfl_xor(v, 4);
  v += __shfl_xor(v, 2);
  v += __shfl_xor(v, 1);
  return v;
}

// ---------------------------------------------------------------------------
// K1: MLP -> weights -> mixed.  32 b per wg, 256 threads.
// ---------------------------------------------------------------------------
__global__ __launch_bounds__(256) void k_prep(
    const float* __restrict__ s, const float* __restrict__ t2s,
    const float* __restrict__ w1, const float* __restrict__ w2,
    const float* __restrict__ w3, const float* __restrict__ gthr,
    float* __restrict__ mixed_ws)
{
  __shared__ float sT[64][36];    // [k][b], padded
  __shared__ float hT[256][36];   // [c][b], holds h1 then h2

  const int tid = threadIdx.x;
  const int b0  = blockIdx.x * 32;

  #pragma unroll
  for (int i = 0; i < 8; i++) {
    int flat = tid + i * 256;
    int bl = flat >> 6, k = flat & 63;
    sT[k][bl] = s[(size_t)(b0 + bl) * 64 + k];
  }
  __syncthreads();

  const int cg = tid & 31, bg = tid >> 5;
  const int c0 = cg * 8, bb0 = bg * 4;

  // ---- h1 = 1.679*silu(s@W1/8), tile 4b x 8c ----
  float acc[4][8];
  #pragma unroll
  for (int j = 0; j < 4; j++)
    #pragma unroll
    for (int i = 0; i < 8; i++) acc[j][i] = 0.f;

  for (int k = 0; k < 64; k++) {
    float4 bv = *(const float4*)&sT[k][bb0];
    float4 wa = *(const float4*)&w1[k * 256 + c0];
    float4 wb = *(const float4*)&w1[k * 256 + c0 + 4];
    const float bvv[4] = {bv.x, bv.y, bv.z, bv.w};
    #pragma unroll
    for (int j = 0; j < 4; j++) { FMA8(acc[j], wa, wb, bvv[j]); }
  }
  #pragma unroll
  for (int j = 0; j < 4; j++)
    #pragma unroll
    for (int i = 0; i < 8; i++)
      hT[c0 + i][bb0 + j] = act_silu(acc[j][i] * 0.125f);
  __syncthreads();

  // ---- h2 = 1.679*silu(h1@W2/16) ----
  float acc2[4][8];
  #pragma unroll
  for (int j = 0; j < 4; j++)
    #pragma unroll
    for (int i = 0; i < 8; i++) acc2[j][i] = 0.f;

  for (int k = 0; k < 256; k++) {
    float4 bv = *(const float4*)&hT[k][bb0];
    float4 wa = *(const float4*)&w2[k * 256 + c0];
    float4 wb = *(const float4*)&w2[k * 256 + c0 + 4];
    const float bvv[4] = {bv.x, bv.y, bv.z, bv.w};
    #pragma unroll
    for (int j = 0; j < 4; j++) { FMA8(acc2[j], wa, wb, bvv[j]); }
  }
  __syncthreads();   // all h1 reads done before overwrite
  #pragma unroll
  for (int j = 0; j < 4; j++)
    #pragma unroll
    for (int i = 0; i < 8; i++)
      hT[c0 + i][bb0 + j] = act_silu(acc2[j][i] * 0.0625f);
  __syncthreads();

  // ---- rel = h2@W3/16 ; gate ; weights ; mixed ----
  const int jj  = tid & 31;   // kernel index
  const int blg = tid >> 5;   // 8 b-groups of 4
  float acc3[4] = {0.f, 0.f, 0.f, 0.f};
  for (int k = 0; k < 256; k++) {
    float wv  = w3[k * 32 + jj];
    float4 hv = *(const float4*)&hT[k][blg * 4];
    acc3[0] = fmaf(hv.x, wv, acc3[0]);
    acc3[1] = fmaf(hv.y, wv, acc3[1]);
    acc3[2] = fmaf(hv.z, wv, acc3[2]);
    acc3[3] = fmaf(hv.w, wv, acc3[3]);
  }
  const float thrv = gthr[jj];
  #pragma unroll
  for (int r = 0; r < 4; r++) {
    int bl = blg * 4 + r;
    int b  = b0 + bl;
    float rel = acc3[r] * 0.0625f;
    const float* tp = t2s + (size_t)(b * 32 + jj) * 5;
    float tv0 = tp[0], tv1 = tp[1], tv2 = tp[2], tv3 = tp[3], tv4 = tp[4];
    float mag  = sqrtf(tv0*tv0 + tv1*tv1 + tv2*tv2 + tv3*tv3 + tv4*tv4);
    float gate = mag / (mag + thrv);
    float w = rel * gate * 0.17677669529663687f;  // 1/sqrt(32)
    float pm0 = w*tv0, pm1 = w*tv1, pm2 = w*tv2, pm3 = w*tv3, pm4 = w*tv4;
    #pragma unroll
    for (int off = 16; off >= 1; off >>= 1) {
      pm0 += __shfl_xor(pm0, off);
      pm1 += __shfl_xor(pm1, off);
      pm2 += __shfl_xor(pm2, off);
      pm3 += __shfl_xor(pm3, off);
      pm4 += __shfl_xor(pm4, off);
    }
    if (jj == 0) {
      float* mp = mixed_ws + (size_t)b * 5;
      mp[0] = pm0; mp[1] = pm1; mp[2] = pm2; mp[3] = pm3; mp[4] = pm4;
    }
  }
}

// ---------------------------------------------------------------------------
// K2: transpose tp2_w202 (128x128).
// ---------------------------------------------------------------------------
__global__ __launch_bounds__(256) void k_transpose(
    const float* __restrict__ in, float* __restrict__ out)
{
  int idx = blockIdx.x * 256 + threadIdx.x;  // 16384
  int u = idx >> 7, v = idx & 127;
  out[v * 128 + u] = in[u * 128 + v];
}

// ---------------------------------------------------------------------------
// K3: symmetrize tp1_w000 into packed upper-triangular (2080 pairs x 128).
// ---------------------------------------------------------------------------
__global__ __launch_bounds__(256) void k_symW000(
    const float* __restrict__ w, float* __restrict__ wsym)
{
  int u = blockIdx.x;  // 64 blocks
  int base = u * 64 - (u * (u - 1)) / 2;
  int n = (64 - u) * 128;
  for (int idx = threadIdx.x; idx < n; idx += 256) {
    int t = idx >> 7, wc = idx & 127;
    int v = u + t;
    float val = w[(size_t)(u * 64 + v) * 128 + wc];
    if (v > u) val += w[(size_t)(v * 64 + u) * 128 + wc];
    wsym[(size_t)(base + t) * 128 + wc] = val;
  }
}

// ---------------------------------------------------------------------------
// K4a (split): y-builder. 16 b per block, 512 threads, ~39 KB LDS.
// thread = (bl 0..15, xw 0..31), each owns 4 w-columns.
// ---------------------------------------------------------------------------
__global__ __launch_bounds__(512) void k_y(
    const float* __restrict__ s, const float* __restrict__ t2s,
    const float* __restrict__ wsym, const float* __restrict__ w220,
    const float* __restrict__ w022, const float* __restrict__ w202,
    const float* __restrict__ w222,
    float* __restrict__ y0_ws, float* __restrict__ y2_ws, Coefs cf)
{
  __shared__ float sL[16][68];           // 4.4 KB (68*4=272 B row, 16B-aligned)
  __shared__ float tL[16][16][8];        // 8.2 KB
  __shared__ float grA[16][16][16];      // 16 KB  gram for all (u,v)
  __shared__ float GL[16][25];           // 1.6 KB
  __shared__ float QL[16][16][5];        // 5.1 KB
  __shared__ float cL222[125];           // 0.5 KB
  __shared__ unsigned char u8t[2080], v8t[2080];  // 4.2 KB

  const int tid = threadIdx.x;
  const int b0  = blockIdx.x * 16;

  float dk022[5], dk202[5], dk220[5];
  #pragma unroll
  for (int k = 0; k < 5; k++) {
    dk022[k] = cf.d022[k]; dk202[k] = cf.d202[k]; dk220[k] = cf.d220[k];
  }

  if (tid == 0) {
    #pragma unroll
    for (int i = 0; i < 125; i++) cL222[i] = cf.c222[i];
  }
  for (int idx = tid; idx < 16 * 64; idx += 512) {
    int bl = idx >> 6, k = idx & 63;
    sL[bl][k] = s[(size_t)(b0 + bl) * 64 + k];
  }
  for (int idx = tid; idx < 16 * 80; idx += 512) {
    int bl = idx / 80, rem = idx - bl * 80;
    int u = rem / 5, m = rem - u * 5;
    int b = b0 + bl;
    float v;
    if (u < 15) v = t2s[(size_t)(b * 32 + u) * 5 + m];
    else {
      v = 0.f;
      for (int kk = 0; kk < 32; kk++) v += t2s[(size_t)(b * 32 + kk) * 5 + m];
    }
    tL[bl][u][m] = v;
  }
  if (tid < 64) {  // pair-index tables
    int u = tid;
    int base = u * 64 - (u * (u - 1)) / 2;
    for (int t = 0; t < 64 - u; t++) {
      u8t[base + t] = (unsigned char)u;
      v8t[base + t] = (unsigned char)(u + t);
    }
  }
  __syncthreads();

  // gram for all u,v (used by y220)
  for (int idx = tid; idx < 16 * 256; idx += 512) {
    int bb = idx >> 8, r = idx & 255;
    int u = r >> 4, v = r & 15;
    float g = 0.f;
    #pragma unroll
    for (int m = 0; m < 5; m++)
      g = fmaf(dk220[m] * tL[bb][u][m], tL[bb][v][m], g);
    grA[bb][u][v] = g;
  }
  __syncthreads();

  const int xw = tid & 31;
  const int bl = tid >> 5;
  const int w0 = xw * 4;

  // ---- y000: flat pair loop, unroll 8 for load pipelining ----
  float y0acc[4] = {0.f, 0.f, 0.f, 0.f};
  #pragma unroll 8
  for (int p = 0; p < 2080; p++) {
    int u = u8t[p], v = v8t[p];
    float prod = sL[bl][u] * sL[bl][v];
    float4 w4 = *(const float4*)(wsym + (size_t)p * 128 + w0);
    FMA4(y0acc, w4, prod);
  }
  // ---- y220: flat 256 loop ----
  #pragma unroll 8
  for (int q = 0; q < 256; q++) {
    float gv = grA[bl][q >> 4][q & 15];
    float4 w4 = *(const float4*)(w220 + (size_t)q * 128 + w0);
    FMA4(y0acc, w4, gv);
  }
  {
    float4 o;
    o.x = cf.a0 * y0acc[0]; o.y = cf.a0 * y0acc[1];
    o.z = cf.a0 * y0acc[2]; o.w = cf.a0 * y0acc[3];
    *(float4*)(y0_ws + (size_t)(b0 + bl) * 128 + w0) = o;
  }

  // ---- y2 ----
  float y2acc[5][4];
  #pragma unroll
  for (int k = 0; k < 5; k++)
    #pragma unroll
    for (int wi = 0; wi < 4; wi++) y2acc[k][wi] = 0.f;

  // tp022
  for (int v = 0; v < 16; v++) {
    float a4[4] = {0.f, 0.f, 0.f, 0.f};
    #pragma unroll 8
    for (int u = 0; u < 64; u++) {
      float su = sL[bl][u];
      float4 w4 = *(const float4*)(w022 + (size_t)(u * 16 + v) * 128 + w0);
      FMA4(a4, w4, su);
    }
    #pragma unroll
    for (int k = 0; k < 5; k++) {
      float fk = dk022[k] * tL[bl][v][k];
      #pragma unroll
      for (int wi = 0; wi < 4; wi++) y2acc[k][wi] = fmaf(fk, a4[wi], y2acc[k][wi]);
    }
  }
  // tp202
  for (int u = 0; u < 16; u++) {
    float a4[4] = {0.f, 0.f, 0.f, 0.f};
    #pragma unroll 8
    for (int v = 0; v < 64; v++) {
      float sv = sL[bl][v];
      float4 w4 = *(const float4*)(w202 + (size_t)(u * 64 + v) * 128 + w0);
      FMA4(a4, w4, sv);
    }
    #pragma unroll
    for (int k = 0; k < 5; k++) {
      float fk = dk202[k] * tL[bl][u][k];
      #pragma unroll
      for (int wi = 0; wi < 4; wi++) y2acc[k][wi] = fmaf(fk, a4[wi], y2acc[k][wi]);
    }
  }
  // tp222
  for (int u = 0; u < 16; u++) {
    if (tid < 400) {
      int bb = tid / 25, jk = tid - bb * 25;
      float g = 0.f;
      #pragma unroll
      for (int ii = 0; ii < 5; ii++)
        g = fmaf(cL222[ii * 25 + jk], tL[bb][u][ii], g);
      GL[bb][jk] = g;
    }
    __syncthreads();
    for (int idx = tid; idx < 1280; idx += 512) {
      int bb = idx / 80, rem = idx - bb * 80;
      int vv = rem / 5, kk = rem - vv * 5;
      float q = 0.f;
      #pragma unroll
      for (int jj = 0; jj < 5; jj++)
        q = fmaf(GL[bb][jj * 5 + kk], tL[bb][vv][jj], q);
      QL[bb][vv][kk] = q;
    }
    __syncthreads();
    #pragma unroll 4
    for (int v = 0; v < 16; v++) {
      float4 w4 = *(const float4*)(w222 + (size_t)(u * 16 + v) * 128 + w0);
      #pragma unroll
      for (int k = 0; k < 5; k++) {
        float qv = QL[bl][v][k];
        FMA4(y2acc[k], w4, qv);
      }
    }
    __syncthreads();
  }
  #pragma unroll
  for (int k = 0; k < 5; k++) {
    float4 o;
    o.x = cf.a2 * y2acc[k][0]; o.y = cf.a2 * y2acc[k][1];
    o.z = cf.a2 * y2acc[k][2]; o.w = cf.a2 * y2acc[k][3];
    *(float4*)(y2_ws + ((size_t)(b0 + bl) * 5 + k) * 128 + w0) = o;
  }
}

// ---------------------------------------------------------------------------
// K4b (split): tp2 contractions + epilogue. 16 b per block, 512 threads.
// thread = (xv 0..127, g4 0..3), each group handles 4 b's.
// ---------------------------------------------------------------------------
__global__ __launch_bounds__(512) void k_tp2(
    const float* __restrict__ y0_ws, const float* __restrict__ y2_ws,
    const float* __restrict__ mixed_ws,
    const float* __restrict__ w2022, const float* __restrict__ w202T,
    const float* __restrict__ w2222,
    const float* __restrict__ csc, float* __restrict__ out, Coefs cf)
{
  __shared__ float y0L[16][128];       //  8.2 KB
  __shared__ float y2L[16][5][128];    // 41 KB
  __shared__ float cL222[125];
  __shared__ float corrAcc[16][5];
  __shared__ float pPL[16][25];

  const int tid = threadIdx.x;
  const int b0  = blockIdx.x * 16;

  float dk022[5], dk202[5];
  #pragma unroll
  for (int k = 0; k < 5; k++) { dk022[k] = cf.d022[k]; dk202[k] = cf.d202[k]; }

  if (tid == 0) {
    #pragma unroll
    for (int i = 0; i < 125; i++) cL222[i] = cf.c222[i];
  }
  // stage y0 (2048 floats = 512 float4) and y2 (10240 floats = 2560 float4)
  ((float4*)y0L)[tid] = *(const float4*)(y0_ws + (size_t)b0 * 128 + tid * 4);
  for (int idx = tid; idx < 2560; idx += 512)
    ((float4*)y2L)[idx] = *(const float4*)(y2_ws + (size_t)b0 * 5 * 128 + (size_t)idx * 4);
  if (tid < 80)  corrAcc[tid / 5][tid % 5] = 0.f;
  if (tid < 400) pPL[tid / 25][tid % 25] = 0.f;
  __syncthreads();

  const int xv = tid & 127;
  const int g4 = tid >> 7;   // 0..3, 4 b's each

  // ---- gv[v] = sum_u W2022[u,v] y0[u]; fold d022[k]*sum_v gv*y2[:,k,v] ----
  {
    float gAcc[4] = {0.f, 0.f, 0.f, 0.f};
    for (int u4 = 0; u4 < 32; u4++) {
      float wv[4];
      #pragma unroll
      for (int uu = 0; uu < 4; uu++) wv[uu] = w2022[(size_t)(u4 * 4 + uu) * 128 + xv];
      #pragma unroll
      for (int r = 0; r < 4; r++) {
        float4 yv = *(const float4*)&y0L[g4 * 4 + r][u4 * 4];
        gAcc[r] = fmaf(wv[0], yv.x, gAcc[r]);
        gAcc[r] = fmaf(wv[1], yv.y, gAcc[r]);
        gAcc[r] = fmaf(wv[2], yv.z, gAcc[r]);
        gAcc[r] = fmaf(wv[3], yv.w, gAcc[r]);
      }
    }
    #pragma unroll
    for (int r = 0; r < 4; r++) {
      int b = g4 * 4 + r;
      #pragma unroll
      for (int k = 0; k < 5; k++) {
        float v = waveReduce64(gAcc[r] * y2L[b][k][xv]);
        if ((tid & 63) == 0) atomicAdd(&corrAcc[b][k], dk022[k] * v);
      }
    }
  }
  // ---- hv[u] = sum_v W2202[u,v] y0[v] (via W202T); fold d202 ----
  {
    float hAcc[4] = {0.f, 0.f, 0.f, 0.f};
    for (int v4 = 0; v4 < 32; v4++) {
      float wv[4];
      #pragma unroll
      for (int vv = 0; vv < 4; vv++) wv[vv] = w202T[(size_t)(v4 * 4 + vv) * 128 + xv];
      #pragma unroll
      for (int r = 0; r < 4; r++) {
        float4 yv = *(const float4*)&y0L[g4 * 4 + r][v4 * 4];
        hAcc[r] = fmaf(wv[0], yv.x, hAcc[r]);
        hAcc[r] = fmaf(wv[1], yv.y, hAcc[r]);
        hAcc[r] = fmaf(wv[2], yv.z, hAcc[r]);
        hAcc[r] = fmaf(wv[3], yv.w, hAcc[r]);
      }
    }
    #pragma unroll
    for (int r = 0; r < 4; r++) {
      int b = g4 * 4 + r;
      #pragma unroll
      for (int k = 0; k < 5; k++) {
        float v = waveReduce64(hAcc[r] * y2L[b][k][xv]);
        if ((tid & 63) == 0) atomicAdd(&corrAcc[b][k], dk202[k] * v);
      }
    }
  }
  // ---- Zi[v,i] = sum_u W2222[u,v] y2[u,i]; P[i,j] = sum_v Zi[v,i] y2[v,j] ----
  for (int i = 0; i < 5; i++) {
    float zAcc[4] = {0.f, 0.f, 0.f, 0.f};
    for (int u4 = 0; u4 < 32; u4++) {
      float wv[4];
      #pragma unroll
      for (int uu = 0; uu < 4; uu++) wv[uu] = w2222[(size_t)(u4 * 4 + uu) * 128 + xv];
      #pragma unroll
      for (int r = 0; r < 4; r++) {
        float4 yv = *(const float4*)&y2L[g4 * 4 + r][i][u4 * 4];
        zAcc[r] = fmaf(wv[0], yv.x, zAcc[r]);
        zAcc[r] = fmaf(wv[1], yv.y, zAcc[r]);
        zAcc[r] = fmaf(wv[2], yv.z, zAcc[r]);
        zAcc[r] = fmaf(wv[3], yv.w, zAcc[r]);
      }
    }
    #pragma unroll
    for (int r = 0; r < 4; r++) {
      int b = g4 * 4 + r;
      #pragma unroll
      for (int jj = 0; jj < 5; jj++) {
        float v = waveReduce64(zAcc[r] * y2L[b][jj][xv]);
        if ((tid & 63) == 0) atomicAdd(&pPL[b][i * 5 + jj], v);
      }
    }
  }
  __syncthreads();

  if (tid < 80) {
    int bb = tid / 5, k = tid - bb * 5;
    float c2 = 0.f;
    #pragma unroll
    for (int ii = 0; ii < 5; ii++)
      #pragma unroll
      for (int jj = 0; jj < 5; jj++)
        c2 = fmaf(cL222[ii * 25 + jj * 5 + k], pPL[bb][ii * 5 + jj], c2);
    float tot = corrAcc[bb][k] + c2;
    int b = b0 + bb;
    out[(size_t)b * 5 + k] = mixed_ws[(size_t)b * 5 + k] + csc[0] * cf.b2 * tot;
  }
}

// ---------------------------------------------------------------------------
// K4 (fallback fused, round-3): 32 b per wg, 512 threads, 143 KB LDS.
// ---------------------------------------------------------------------------
__global__ __launch_bounds__(512) void k_main(
    const float* __restrict__ s, const float* __restrict__ t2s,
    const float* __restrict__ mixed_ws,
    const float* __restrict__ wsym,  const float* __restrict__ w220,
    const float* __restrict__ w022,  const float* __restrict__ w202,
    const float* __restrict__ w222,
    const float* __restrict__ w2022, const float* __restrict__ w202T,
    const float* __restrict__ w2222,
    const float* __restrict__ csc, float* __restrict__ out, Coefs cf)
{
  __shared__ float sL[32][68];
  __shared__ float tL[32][16][8];
  __shared__ float y0L[32][128];
  __shared__ float y2L[32][5][128];
  __shared__ float grL[32][16];
  __shared__ float GL[32][25];
  __shared__ float QL[32][16][5];
  __shared__ float cL222[125];
  __shared__ float corrAcc[32][5];
  __shared__ float pPL[32][25];

  const int tid = threadIdx.x;
  const int b0  = blockIdx.x * 32;

  float dk022[5], dk202[5], dk220[5];
  #pragma unroll
  for (int k = 0; k < 5; k++) {
    dk022[k] = cf.d022[k]; dk202[k] = cf.d202[k]; dk220[k] = cf.d220[k];
  }

  if (tid == 0) {
    #pragma unroll
    for (int i = 0; i < 125; i++) cL222[i] = cf.c222[i];
  }
  for (int idx = tid; idx < 2048; idx += 512) {
    int bl = idx >> 6, k = idx & 63;
    sL[bl][k] = s[(size_t)(b0 + bl) * 64 + k];
  }
  for (int idx = tid; idx < 2560; idx += 512) {
    int bl = idx / 80, rem = idx - bl * 80;
    int u = rem / 5, m = rem - u * 5;
    int b = b0 + bl;
    float v;
    if (u < 15) v = t2s[(size_t)(b * 32 + u) * 5 + m];
    else {
      v = 0.f;
      for (int kk = 0; kk < 32; kk++) v += t2s[(size_t)(b * 32 + kk) * 5 + m];
    }
    tL[bl][u][m] = v;
  }
  for (int idx = tid; idx < 160; idx += 512) corrAcc[idx / 5][idx % 5] = 0.f;
  for (int idx = tid; idx < 800; idx += 512) pPL[idx / 25][idx % 25] = 0.f;
  __syncthreads();

  const int xw = tid & 15;
  const int bl = tid >> 4;
  const int w0 = xw * 8;

  float y0acc[8] = {0.f,0.f,0.f,0.f,0.f,0.f,0.f,0.f};
  {
    int base = 0;
    for (int u = 0; u < 64; u++) {
      const int len = 64 - u;
      float su = sL[bl][u];
      float z[8] = {0.f,0.f,0.f,0.f,0.f,0.f,0.f,0.f};
      const float* Wu = wsym + (size_t)base * 128 + w0;
      for (int t = 0; t < len; t++) {
        float sv = sL[bl][u + t];
        const float* p = Wu + (size_t)t * 128;
        float4 wa = *(const float4*)p;
        float4 wb = *(const float4*)(p + 4);
        FMA8(z, wa, wb, sv);
      }
      #pragma unroll
      for (int wi = 0; wi < 8; wi++) y0acc[wi] = fmaf(su, z[wi], y0acc[wi]);
      base += len;
    }
  }
  for (int u = 0; u < 16; u++) {
    {
      int bb = tid >> 4, vv = tid & 15;
      float g = 0.f;
      #pragma unroll
      for (int m = 0; m < 5; m++)
        g = fmaf(dk220[m] * tL[bb][u][m], tL[bb][vv][m], g);
      grL[bb][vv] = g;
    }
    __syncthreads();
    const float* Wu = w220 + (size_t)(u * 16) * 128 + w0;
    for (int v = 0; v < 16; v++) {
      float gv = grL[bl][v];
      const float* p = Wu + (size_t)v * 128;
      float4 wa = *(const float4*)p;
      float4 wb = *(const float4*)(p + 4);
      FMA8(y0acc, wa, wb, gv);
    }
    __syncthreads();
  }
  #pragma unroll
  for (int wi = 0; wi < 8; wi++) y0L[bl][w0 + wi] = cf.a0 * y0acc[wi];

  float y2acc[5][8];
  #pragma unroll
  for (int k = 0; k < 5; k++)
    #pragma unroll
    for (int wi = 0; wi < 8; wi++) y2acc[k][wi] = 0.f;

  for (int v = 0; v < 16; v++) {
    float accA[8] = {0.f,0.f,0.f,0.f,0.f,0.f,0.f,0.f};
    for (int u4 = 0; u4 < 16; u4++) {
      float4 s4 = *(const float4*)&sL[bl][u4 * 4];
      const float sv[4] = {s4.x, s4.y, s4.z, s4.w};
      #pragma unroll
      for (int ui = 0; ui < 4; ui++) {
        const float* p = w022 + (size_t)((u4 * 4 + ui) * 16 + v) * 128 + w0;
        float4 wa = *(const float4*)p;
        float4 wb = *(const float4*)(p + 4);
        FMA8(accA, wa, wb, sv[ui]);
      }
    }
    #pragma unroll
    for (int k = 0; k < 5; k++) {
      float fk = dk022[k] * tL[bl][v][k];
      #pragma unroll
      for (int wi = 0; wi < 8; wi++) y2acc[k][wi] = fmaf(fk, accA[wi], y2acc[k][wi]);
    }
  }
  for (int u = 0; u < 16; u++) {
    float accB[8] = {0.f,0.f,0.f,0.f,0.f,0.f,0.f,0.f};
    for (int v4 = 0; v4 < 16; v4++) {
      float4 s4 = *(const float4*)&sL[bl][v4 * 4];
      const float sv[4] = {s4.x, s4.y, s4.z, s4.w};
      #pragma unroll
      for (int vi = 0; vi < 4; vi++) {
        const float* p = w202 + (size_t)(u * 64 + v4 * 4 + vi) * 128 + w0;
        float4 wa = *(const float4*)p;
        float4 wb = *(const float4*)(p + 4);
        FMA8(accB, wa, wb, sv[vi]);
      }
    }
    #pragma unroll
    for (int k = 0; k < 5; k++) {
      float fk = dk202[k] * tL[bl][u][k];
      #pragma unroll
      for (int wi = 0; wi < 8; wi++) y2acc[k][wi] = fmaf(fk, accB[wi], y2acc[k][wi]);
    }
  }
  for (int u = 0; u < 16; u++) {
    for (int idx = tid; idx < 800; idx += 512) {
      int bb = idx / 25, jk = idx - bb * 25;
      float g = 0.f;
      #pragma unroll
      for (int ii = 0; ii < 5; ii++)
        g = fmaf(cL222[ii * 25 + jk], tL[bb][u][ii], g);
      GL[bb][jk] = g;
    }
    __syncthreads();
    for (int idx = tid; idx < 2560; idx += 512) {
      int bb = idx / 80, rem = idx - bb * 80;
      int vv = rem / 5, kk = rem - vv * 5;
      float q = 0.f;
      #pragma unroll
      for (int jj = 0; jj < 5; jj++)
        q = fmaf(GL[bb][jj * 5 + kk], tL[bb][vv][jj], q);
      QL[bb][vv][kk] = q;
    }
    __syncthreads();
    for (int v = 0; v < 16; v++) {
      const float* p = w222 + (size_t)(u * 16 + v) * 128 + w0;
      float4 wa = *(const float4*)p;
      float4 wb = *(const float4*)(p + 4);
      #pragma unroll
      for (int k = 0; k < 5; k++) {
        float qv = QL[bl][v][k];
        FMA8(y2acc[k], wa, wb, qv);
      }
    }
    __syncthreads();
  }
  #pragma unroll
  for (int k = 0; k < 5; k++)
    #pragma unroll
    for (int wi = 0; wi < 8; wi++)
      y2L[bl][k][w0 + wi] = cf.a2 * y2acc[k][wi];
  __syncthreads();

  const int xv = tid & 127;
  const int g4 = tid >> 7;

  {
    float gAcc[8] = {0.f,0.f,0.f,0.f,0.f,0.f,0.f,0.f};
    for (int u4 = 0; u4 < 32; u4++) {
      float wv[4];
      #pragma unroll
      for (int uu = 0; uu < 4; uu++) wv[uu] = w2022[(size_t)(u4 * 4 + uu) * 128 + xv];
      #pragma unroll
      for (int r = 0; r < 8; r++) {
        float4 yv = *(const float4*)&y0L[g4 * 8 + r][u4 * 4];
        gAcc[r] = fmaf(wv[0], yv.x, gAcc[r]);
        gAcc[r] = fmaf(wv[1], yv.y, gAcc[r]);
        gAcc[r] = fmaf(wv[2], yv.z, gAcc[r]);
        gAcc[r] = fmaf(wv[3], yv.w, gAcc[r]);
      }
    }
    #pragma unroll
    for (int r = 0; r < 8; r++) {
      int b = g4 * 8 + r;
      #pragma unroll
      for (int k = 0; k < 5; k++) {
        float v = waveReduce64(gAcc[r] * y2L[b][k][xv]);
        if ((tid & 63) == 0) atomicAdd(&corrAcc[b][k], dk022[k] * v);
      }
    }
  }
  {
    float hAcc[8] = {0.f,0.f,0.f,0.f,0.f,0.f,0.f,0.f};
    for (int v4 = 0; v4 < 32; v4++) {
      float wv[4];
      #pragma unroll
      for (int vv = 0; vv < 4; vv++) wv[vv] = w202T[(size_t)(v4 * 4 + vv) * 128 + xv];
      #pragma unroll
      for (int r = 0; r < 8; r++) {
        float4 yv = *(const float4*)&y0L[g4 * 8 + r][v4 * 4];
        hAcc[r] = fmaf(wv[0], yv.x, hAcc[r]);
        hAcc[r] = fmaf(wv[1], yv.y, hAcc[r]);
        hAcc[r] = fmaf(wv[2], yv.z, hAcc[r]);
        hAcc[r] = fmaf(wv[3], yv.w, hAcc[r]);
      }
    }
    #pragma unroll
    for (int r = 0; r < 8; r++) {
      int b = g4 * 8 + r;
      #pragma unroll
      for (int k = 0; k < 5; k++) {
        float v = waveReduce64(hAcc[r] * y2L[b][k][xv]);
        if ((tid & 63) == 0) atomicAdd(&corrAcc[b][k], dk202[k] * v);
      }
    }
  }
  for (int i = 0; i < 5; i++) {
    float zAcc[8] = {0.f,0.f,0.f,0.f,0.f,0.f,0.f,0.f};
    for (int u4 = 0; u4 < 32; u4++) {
      float wv[4];
      #pragma unroll
      for (int uu = 0; uu < 4; uu++) wv[uu] = w2222[(size_t)(u4 * 4 + uu) * 128 + xv];
      #pragma unroll
      for (int r = 0; r < 8; r++) {
        float4 yv = *(const float4*)&y2L[g4 * 8 + r][i][u4 * 4];
        zAcc[r] = fmaf(wv[0], yv.x, zAcc[r]);
        zAcc[r] = fmaf(wv[1], yv.y, zAcc[r]);
        zAcc[r] = fmaf(wv[2], yv.z, zAcc[r]);
        zAcc[r] = fmaf(wv[3], yv.w, zAcc[r]);
      }
    }
    #pragma unroll
    for (int r = 0; r < 8; r++) {
      int b = g4 * 8 + r;
      #pragma unroll
      for (int jj = 0; jj < 5; jj++) {
        float v = waveReduce64(zAcc[r] * y2L[b][jj][xv]);
        if ((tid & 63) == 0) atomicAdd(&pPL[b][i * 5 + jj], v);
      }
    }
  }
  __syncthreads();

  if (tid < 160) {
    int bb = tid / 5, k = tid - bb * 5;
    float c2 = 0.f;
    #pragma unroll
    for (int ii = 0; ii < 5; ii++)
      #pragma unroll
      for (int jj = 0; jj < 5; jj++)
        c2 = fmaf(cL222[ii * 25 + jj * 5 + k], pPL[bb][ii * 5 + jj], c2);
    float tot = corrAcc[bb][k] + c2;
    int b = b0 + bb;
    out[(size_t)b * 5 + k] = mixed_ws[(size_t)b * 5 + k] + csc[0] * cf.b2 * tot;
  }
}

// ---------------------------------------------------------------------------
// Host: replicate reference's wigner-3j computation (RREF null space).
// ---------------------------------------------------------------------------
namespace {

using cplx = std::complex<double>;

static void su2_gen(int l, std::vector<cplx>& Jx, std::vector<cplx>& Jy,
                    std::vector<cplx>& Jz) {
  int d = 2 * l + 1;
  Jx.assign((size_t)d * d, cplx(0, 0));
  Jy.assign((size_t)d * d, cplx(0, 0));
  Jz.assign((size_t)d * d, cplx(0, 0));
  for (int a = 0; a < d; a++) Jz[(size_t)a * d + a] = cplx(a - l, 0);
  for (int r = 1; r < d; r++) {
    double m = (r - 1) - l;
    double v = std::sqrt(l * (l + 1.0) - m * (m + 1.0));
    Jx[(size_t)r * d + (r - 1)] += cplx(v / 2, 0);
    Jx[(size_t)(r - 1) * d + r] += cplx(v / 2, 0);
    Jy[(size_t)r * d + (r - 1)] += cplx(0, -v / 2);
    Jy[(size_t)(r - 1) * d + r] += cplx(0, v / 2);
  }
}

static void real_basis(int l, std::vector<cplx>& U) {
  int d = 2 * l + 1;
  U.assign((size_t)d * d, cplx(0, 0));
  U[(size_t)l * d + l] = cplx(1, 0);
  double is2 = 1.0 / std::sqrt(2.0);
  for (int m = 1; m <= l; m++) {
    double sgn = (m % 2 == 0) ? 1.0 : -1.0;
    U[(size_t)(l + m) * d + (l + m)] = cplx(sgn * is2, 0);
    U[(size_t)(l + m) * d + (l - m)] = cplx(is2, 0);
    U[(size_t)(l - m) * d + (l - m)] = cplx(0, is2);
    U[(size_t)(l - m) * d + (l + m)] = cplx(0, -sgn * is2);
  }
}

static void real_gens(int l, std::vector<double> G[3]) {
  int d = 2 * l + 1;
  if (l == 0) { for (int a = 0; a < 3; a++) G[a].assign(1, 0.0); return; }
  std::vector<cplx> J[3];
  su2_gen(l, J[0], J[1], J[2]);
  std::vector<cplx> U;
  real_basis(l, U);
  for (int a = 0; a < 3; a++) {
    std::vector<cplx> T((size_t)d * d, cplx(0, 0));
    for (int i = 0; i < d; i++)
      for (int k = 0; k < d; k++) {
        cplx s(0, 0);
        for (int j = 0; j < d; j++)
          s += U[(size_t)i * d + j] * (cplx(0, -1) * J[a][(size_t)j * d + k]);
        T[(size_t)i * d + k] = s;
      }
    G[a].assign((size_t)d * d, 0.0);
    for (int i = 0; i < d; i++)
      for (int k = 0; k < d; k++) {
        cplx s(0, 0);
        for (int j = 0; j < d; j++)
          s += T[(size_t)i * d + j] * std::conj(U[(size_t)k * d + j]);
        G[a][(size_t)i * d + k] = s.real();
      }
  }
}

static void w3j_host(int l1, int l2, int l3, float* out) {
  int d1 = 2 * l1 + 1, d2 = 2 * l2 + 1, d3 = 2 * l3 + 1;
  int D = d1 * d2 * d3;
  std::vector<double> G1[3], G2[3], G3[3];
  real_gens(l1, G1); real_gens(l2, G2); real_gens(l3, G3);
  int R = 3 * D;
  std::vector<double> M((size_t)R * D, 0.0);
  for (int a = 0; a < 3; a++) {
    double* Ma = &M[(size_t)a * D * D];
    for (int i1 = 0; i1 < d1; i1++)
      for (int j1 = 0; j1 < d1; j1++) {
        double g = G1[a][(size_t)i1 * d1 + j1];
        if (g == 0.0) continue;
        for (int i2 = 0; i2 < d2; i2++)
          for (int i3 = 0; i3 < d3; i3++)
            Ma[(size_t)((i1 * d2 + i2) * d3 + i3) * D + ((j1 * d2 + i2) * d3 + i3)] += g;
      }
    for (int i2 = 0; i2 < d2; i2++)
      for (int j2 = 0; j2 < d2; j2++) {
        double g = G2[a][(size_t)i2 * d2 + j2];
        if (g == 0.0) continue;
        for (int i1 = 0; i1 < d1; i1++)
          for (int i3 = 0; i3 < d3; i3++)
            Ma[(size_t)((i1 * d2 + i2) * d3 + i3) * D + ((i1 * d2 + j2) * d3 + i3)] += g;
      }
    for (int i3 = 0; i3 < d3; i3++)
      for (int j3 = 0; j3 < d3; j3++) {
        double g = G3[a][(size_t)i3 * d3 + j3];
        if (g == 0.0) continue;
        for (int i1 = 0; i1 < d1; i1++)
          for (int i2 = 0; i2 < d2; i2++)
            Ma[(size_t)((i1 * d2 + i2) * d3 + i3) * D + ((i1 * d2 + i2) * d3 + j3)] += g;
      }
  }
  std::vector<int> pivcol;
  int rank = 0;
  for (int col = 0; col < D && rank < R; col++) {
    int pr = -1; double pv = 1e-9;
    for (int r = rank; r < R; r++) {
      double av = std::fabs(M[(size_t)r * D + col]);
      if (av > pv) { pv = av; pr = r; }
    }
    if (pr < 0) continue;
    if (pr != rank)
      for (int c = 0; c < D; c++) std::swap(M[(size_t)pr * D + c], M[(size_t)rank * D + c]);
    double inv = 1.0 / M[(size_t)rank * D + col];
    for (int c = 0; c < D; c++) M[(size_t)rank * D + c] *= inv;
    for (int r = 0; r < R; r++) {
      if (r == rank) continue;
      double f = M[(size_t)r * D + col];
      if (f != 0.0)
        for (int c = 0; c < D; c++) M[(size_t)r * D + c] -= f * M[(size_t)rank * D + c];
    }
    pivcol.push_back(col);
    rank++;
  }
  std::vector<char> isp(D, 0);
  for (int c : pivcol) isp[c] = 1;
  int fc = 0;
  for (int c = 0; c < D; c++) if (!isp[c]) { fc = c; break; }
  std::vector<double> x(D, 0.0);
  x[fc] = 1.0;
  for (int r = 0; r < rank; r++) x[pivcol[r]] = -M[(size_t)r * D + fc];
  double n = 0;
  for (double v : x) n += v * v;
  n = std::sqrt(n);
  for (int c = 0; c < D; c++) x[c] /= n;
  double best = 0;
  for (int c = 0; c < D; c++) { double av = std::fabs(x[c]); if (av > best) best = av; }
  double ssum = 0;
  for (int c = 0; c < D; c++) {
    double av = std::fabs(x[c]);
    if (av >= best * 0.999) ssum += (x[c] >= 0 ? 1.0 : -1.0);
  }
  double sgn = (ssum >= 0) ? 1.0 : -1.0;
  for (int c = 0; c < D; c++) out[c] = (float)(x[c] * sgn);
}

}  // namespace

// ---------------------------------------------------------------------------
extern "C" void kernel_launch(void* const* d_in, const int* in_sizes, int n_in,
                              void* d_out, int out_size, void* d_ws, size_t ws_size,
                              hipStream_t stream)
{
  (void)in_sizes; (void)n_in; (void)out_size;

  const float* s     = (const float*)d_in[0];
  const float* t2s   = (const float*)d_in[1];
  const float* w1    = (const float*)d_in[2];
  const float* w2    = (const float*)d_in[3];
  const float* w3    = (const float*)d_in[4];
  const float* gthr  = (const float*)d_in[5];
  const float* w000  = (const float*)d_in[6];
  const float* w220  = (const float*)d_in[7];
  const float* w022  = (const float*)d_in[8];
  const float* w202  = (const float*)d_in[9];
  const float* w222  = (const float*)d_in[10];
  const float* w2022 = (const float*)d_in[11];
  const float* w2202 = (const float*)d_in[12];
  const float* w2222 = (const float*)d_in[13];
  const float* csc   = (const float*)d_in[14];
  float* out = (float*)d_out;

  char* ws = (char*)d_ws;
  float* mixed_ws = (float*)(ws + MIX_WS_OFF);
  float* w202T    = (float*)(ws + W202T_OFF);
  float* wsym     = (float*)(ws + WSYM_OFF);
  float* y0_ws    = (float*)(ws + Y0_WS_OFF);
  float* y2_ws    = (float*)(ws + Y2_WS_OFF);

  Coefs cf;
  {
    float c000v[1], c022v[25], c202v[25], c220v[25];
    w3j_host(0, 0, 0, c000v);
    w3j_host(0, 2, 2, c022v);
    w3j_host(2, 0, 2, c202v);
    w3j_host(2, 2, 0, c220v);
    w3j_host(2, 2, 2, cf.c222);
    for (int i = 0; i < 125; i++) cf.c222[i] *= C222_FLIP;
    for (int k = 0; k < 5; k++) {
      cf.d022[k] = c022v[k * 5 + k];
      cf.d202[k] = c202v[k * 5 + k];
      cf.d220[k] = c220v[k * 5 + k];
    }
    (void)c000v;
    cf.a0 = (float)std::sqrt(1.0 / (64.0 * 64.0 + 16.0 * 16.0));
    cf.a2 = (float)std::sqrt(5.0 / (2.0 * 64.0 * 16.0 + 16.0 * 16.0));
    cf.b2 = (float)std::sqrt(5.0 / (3.0 * 128.0 * 128.0));
  }

  hipLaunchKernelGGL(k_prep, dim3(512), dim3(256), 0, stream,
                     s, t2s, w1, w2, w3, gthr, mixed_ws);
  hipLaunchKernelGGL(k_transpose, dim3(64), dim3(256), 0, stream, w2202, w202T);
  hipLaunchKernelGGL(k_symW000, dim3(64), dim3(256), 0, stream, w000, wsym);

  if (ws_size >= WS_NEEDED) {
    // split path: occupancy-friendly
    hipLaunchKernelGGL(k_y, dim3(1024), dim3(512), 0, stream,
                       s, t2s, wsym, w220, w022, w202, w222, y0_ws, y2_ws, cf);
    hipLaunchKernelGGL(k_tp2, dim3(1024), dim3(512), 0, stream,
                       y0_ws, y2_ws, mixed_ws, w2022, w202T, w2222, csc, out, cf);
  } else {
    // fallback: round-3 fused kernel
    hipLaunchKernelGGL(k_main, dim3(512), dim3(512), 0, stream,
                       s, t2s, mixed_ws, wsym, w220, w022, w202, w222,
                       w2022, w202T, w2222, csc, out, cf);
  }
}

// Round 5
// 1760.301 us; speedup vs baseline: 2.1307x; 2.1307x over previous
//
#include <hip/hip_runtime.h>
#include <hip/hip_bf16.h>
#include <cmath>
#include <complex>
#include <vector>
#include <cstring>
#include <cstdint>

// ---------------------------------------------------------------------------
// ShieldingT2Model: f32, round 5 — fused single heavy kernel, occupancy-fixed.
// B=16384, NS=64, NK=32, NL=16, HM=256, HC=128, out = (B,5) f32.
//
// History: r3 fused (143KB LDS, 1 blk/CU) = 1994us, VALUBusy 15%.
//          r4 split via ws regressed to 3750us (k_tp2 showed GB-scale
//          FETCH/WRITE ~= scratch spill from 140 chained wave reductions).
// r5: fused again, 16 b/block, ~73KB LDS -> 2 blk/CU (16 waves/CU).
//     Phase-5 redone: LDS-staged matvecs + short shfl reductions,
//     unique writers, no atomics, minimal live registers.
//
// ws (~1.46 MB): mixed @0 (327680) | w202T @327680 (65536) | wsym @393216
// C222 sign: majority-positive canonicalization, then flipped (r2/r3 A/B).
// ---------------------------------------------------------------------------

#define C222_FLIP -1.0f

#define MIX_WS_OFF  0
#define W202T_OFF   327680
#define WSYM_OFF    393216

struct Coefs {
  float c222[125];   // full (2,2,2) real wigner-3j, [i][j][k]
  float d022[5];     // diag of C022[0,:,:]
  float d202[5];     // diag of C202[:,0,:]
  float d220[5];     // diag of C220[:,:,0]
  float a0, a2, b2;
};

#define FMA8(acc, wa, wb, sv) do { \
  acc[0] = fmaf((wa).x, (sv), acc[0]); \
  acc[1] = fmaf((wa).y, (sv), acc[1]); \
  acc[2] = fmaf((wa).z, (sv), acc[2]); \
  acc[3] = fmaf((wa).w, (sv), acc[3]); \
  acc[4] = fmaf((wb).x, (sv), acc[4]); \
  acc[5] = fmaf((wb).y, (sv), acc[5]); \
  acc[6] = fmaf((wb).z, (sv), acc[6]); \
  acc[7] = fmaf((wb).w, (sv), acc[7]); \
} while (0)

#define FMA4(acc, wa, sv) do { \
  acc[0] = fmaf((wa).x, (sv), acc[0]); \
  acc[1] = fmaf((wa).y, (sv), acc[1]); \
  acc[2] = fmaf((wa).z, (sv), acc[2]); \
  acc[3] = fmaf((wa).w, (sv), acc[3]); \
} while (0)

__device__ __forceinline__ float act_silu(float x) {
  return 1.679f * x / (1.0f + expf(-x));   // SILU_NORM * silu(x)
}

// ---------------------------------------------------------------------------
// K1: MLP -> weights -> mixed.  32 b per wg, 256 threads. (unchanged, proven)
// ---------------------------------------------------------------------------
__global__ __launch_bounds__(256) void k_prep(
    const float* __restrict__ s, const float* __restrict__ t2s,
    const float* __restrict__ w1, const float* __restrict__ w2,
    const float* __restrict__ w3, const float* __restrict__ gthr,
    float* __restrict__ mixed_ws)
{
  __shared__ float sT[64][36];    // [k][b], padded
  __shared__ float hT[256][36];   // [c][b], holds h1 then h2

  const int tid = threadIdx.x;
  const int b0  = blockIdx.x * 32;

  #pragma unroll
  for (int i = 0; i < 8; i++) {
    int flat = tid + i * 256;
    int bl = flat >> 6, k = flat & 63;
    sT[k][bl] = s[(size_t)(b0 + bl) * 64 + k];
  }
  __syncthreads();

  const int cg = tid & 31, bg = tid >> 5;
  const int c0 = cg * 8, bb0 = bg * 4;

  float acc[4][8];
  #pragma unroll
  for (int j = 0; j < 4; j++)
    #pragma unroll
    for (int i = 0; i < 8; i++) acc[j][i] = 0.f;

  for (int k = 0; k < 64; k++) {
    float4 bv = *(const float4*)&sT[k][bb0];
    float4 wa = *(const float4*)&w1[k * 256 + c0];
    float4 wb = *(const float4*)&w1[k * 256 + c0 + 4];
    const float bvv[4] = {bv.x, bv.y, bv.z, bv.w};
    #pragma unroll
    for (int j = 0; j < 4; j++) { FMA8(acc[j], wa, wb, bvv[j]); }
  }
  #pragma unroll
  for (int j = 0; j < 4; j++)
    #pragma unroll
    for (int i = 0; i < 8; i++)
      hT[c0 + i][bb0 + j] = act_silu(acc[j][i] * 0.125f);
  __syncthreads();

  float acc2[4][8];
  #pragma unroll
  for (int j = 0; j < 4; j++)
    #pragma unroll
    for (int i = 0; i < 8; i++) acc2[j][i] = 0.f;

  for (int k = 0; k < 256; k++) {
    float4 bv = *(const float4*)&hT[k][bb0];
    float4 wa = *(const float4*)&w2[k * 256 + c0];
    float4 wb = *(const float4*)&w2[k * 256 + c0 + 4];
    const float bvv[4] = {bv.x, bv.y, bv.z, bv.w};
    #pragma unroll
    for (int j = 0; j < 4; j++) { FMA8(acc2[j], wa, wb, bvv[j]); }
  }
  __syncthreads();
  #pragma unroll
  for (int j = 0; j < 4; j++)
    #pragma unroll
    for (int i = 0; i < 8; i++)
      hT[c0 + i][bb0 + j] = act_silu(acc2[j][i] * 0.0625f);
  __syncthreads();

  const int jj  = tid & 31;
  const int blg = tid >> 5;
  float acc3[4] = {0.f, 0.f, 0.f, 0.f};
  for (int k = 0; k < 256; k++) {
    float wv  = w3[k * 32 + jj];
    float4 hv = *(const float4*)&hT[k][blg * 4];
    acc3[0] = fmaf(hv.x, wv, acc3[0]);
    acc3[1] = fmaf(hv.y, wv, acc3[1]);
    acc3[2] = fmaf(hv.z, wv, acc3[2]);
    acc3[3] = fmaf(hv.w, wv, acc3[3]);
  }
  const float thrv = gthr[jj];
  #pragma unroll
  for (int r = 0; r < 4; r++) {
    int bl = blg * 4 + r;
    int b  = b0 + bl;
    float rel = acc3[r] * 0.0625f;
    const float* tp = t2s + (size_t)(b * 32 + jj) * 5;
    float tv0 = tp[0], tv1 = tp[1], tv2 = tp[2], tv3 = tp[3], tv4 = tp[4];
    float mag  = sqrtf(tv0*tv0 + tv1*tv1 + tv2*tv2 + tv3*tv3 + tv4*tv4);
    float gate = mag / (mag + thrv);
    float w = rel * gate * 0.17677669529663687f;  // 1/sqrt(32)
    float pm0 = w*tv0, pm1 = w*tv1, pm2 = w*tv2, pm3 = w*tv3, pm4 = w*tv4;
    #pragma unroll
    for (int off = 16; off >= 1; off >>= 1) {
      pm0 += __shfl_xor(pm0, off);
      pm1 += __shfl_xor(pm1, off);
      pm2 += __shfl_xor(pm2, off);
      pm3 += __shfl_xor(pm3, off);
      pm4 += __shfl_xor(pm4, off);
    }
    if (jj == 0) {
      float* mp = mixed_ws + (size_t)b * 5;
      mp[0] = pm0; mp[1] = pm1; mp[2] = pm2; mp[3] = pm3; mp[4] = pm4;
    }
  }
}

// ---------------------------------------------------------------------------
// K2: transpose tp2_w202 (128x128).
// ---------------------------------------------------------------------------
__global__ __launch_bounds__(256) void k_transpose(
    const float* __restrict__ in, float* __restrict__ out)
{
  int idx = blockIdx.x * 256 + threadIdx.x;  // 16384
  int u = idx >> 7, v = idx & 127;
  out[v * 128 + u] = in[u * 128 + v];
}

// ---------------------------------------------------------------------------
// K3: symmetrize tp1_w000 into packed upper-triangular (2080 pairs x 128).
// ---------------------------------------------------------------------------
__global__ __launch_bounds__(256) void k_symW000(
    const float* __restrict__ w, float* __restrict__ wsym)
{
  int u = blockIdx.x;  // 64 blocks
  int base = u * 64 - (u * (u - 1)) / 2;
  int n = (64 - u) * 128;
  for (int idx = threadIdx.x; idx < n; idx += 256) {
    int t = idx >> 7, wc = idx & 127;
    int v = u + t;
    float val = w[(size_t)(u * 64 + v) * 128 + wc];
    if (v > u) val += w[(size_t)(v * 64 + u) * 128 + wc];
    wsym[(size_t)(base + t) * 128 + wc] = val;
  }
}

// ---------------------------------------------------------------------------
// K4: fused heavy kernel. 16 b per block, 1024 blocks, 512 threads.
// LDS ~73 KB -> 2 blocks/CU (16 waves/CU).
// y-phase thread map: (bl = tid>>5 in 0..15, xw = tid&31), 4 w's per thread.
// phase-5 map: (xv = tid&127 channel, g4 = tid>>7 -> 4 b's).
// ---------------------------------------------------------------------------
__global__ __launch_bounds__(512, 4) void k_fused(
    const float* __restrict__ s, const float* __restrict__ t2s,
    const float* __restrict__ mixed_ws,
    const float* __restrict__ wsym,  const float* __restrict__ w220,
    const float* __restrict__ w022,  const float* __restrict__ w202,
    const float* __restrict__ w222,
    const float* __restrict__ w2022, const float* __restrict__ w202T,
    const float* __restrict__ w2222,
    const float* __restrict__ csc, float* __restrict__ out, Coefs cf)
{
  __shared__ float sL[16][68];                    // 4352 B
  __shared__ float tL[16][16][5];                 // 5120 B
  __shared__ float y0L[16][128];                  // 8192 B
  __shared__ float cL222[125];                    //  500 B
  __shared__ float corrAcc[16][5];                //  320 B
  __shared__ float pPL[16][25];                   // 1600 B
  __shared__ unsigned char u8t[2080], v8t[2080];  // 4160 B
  __shared__ __align__(16) char uni[49152];       // union region
  // union usage (time-disjoint):
  //   y220 phase : grA  = float[16*256]            @ uni
  //   tp222 phase: GLb  = float[16][25]            @ uni
  //                QLb  = float[16][16][5]         @ uni+1664
  //   phase 5    : y2L  = float[16][5][128]        @ uni        (40960 B)
  //                gvL  = float[16][128]           @ uni+40960  ( 8192 B)
  float* grA = (float*)uni;
  float (*GLb)[25]     = (float(*)[25])uni;
  float (*QLb)[16][5]  = (float(*)[16][5])(uni + 1664);
  float (*y2L)[5][128] = (float(*)[5][128])uni;
  float (*gvL)[128]    = (float(*)[128])(uni + 40960);

  const int tid = threadIdx.x;
  const int b0  = blockIdx.x * 16;

  float dk022[5], dk202[5], dk220[5];
  #pragma unroll
  for (int k = 0; k < 5; k++) {
    dk022[k] = cf.d022[k]; dk202[k] = cf.d202[k]; dk220[k] = cf.d220[k];
  }

  // ---- stage ----
  if (tid == 0) {
    #pragma unroll
    for (int i = 0; i < 125; i++) cL222[i] = cf.c222[i];
  }
  for (int idx = tid; idx < 16 * 64; idx += 512) {
    int bl = idx >> 6, k = idx & 63;
    sL[bl][k] = s[(size_t)(b0 + bl) * 64 + k];
  }
  for (int idx = tid; idx < 16 * 80; idx += 512) {
    int bl = idx / 80, rem = idx - bl * 80;
    int u = rem / 5, m = rem - u * 5;
    int b = b0 + bl;
    float v;
    if (u < 15) v = t2s[(size_t)(b * 32 + u) * 5 + m];
    else {
      v = 0.f;
      for (int kk = 0; kk < 32; kk++) v += t2s[(size_t)(b * 32 + kk) * 5 + m];
    }
    tL[bl][u][m] = v;
  }
  if (tid < 64) {  // pair-index tables
    int u = tid;
    int base = u * 64 - (u * (u - 1)) / 2;
    for (int t = 0; t < 64 - u; t++) {
      u8t[base + t] = (unsigned char)u;
      v8t[base + t] = (unsigned char)(u + t);
    }
  }
  __syncthreads();

  // gram for all (u,v) -> grA (union region, consumed by y220 below)
  for (int idx = tid; idx < 16 * 256; idx += 512) {
    int bb = idx >> 8, r = idx & 255;
    int u = r >> 4, v = r & 15;
    float g = 0.f;
    #pragma unroll
    for (int m = 0; m < 5; m++)
      g = fmaf(dk220[m] * tL[bb][u][m], tL[bb][v][m], g);
    grA[bb * 256 + r] = g;
  }
  __syncthreads();

  const int xw = tid & 31;
  const int bl = tid >> 5;
  const int w0 = xw * 4;

  // ---- y000: flat pair loop ----
  float y0acc[4] = {0.f, 0.f, 0.f, 0.f};
  #pragma unroll 8
  for (int p = 0; p < 2080; p++) {
    int u = u8t[p], v = v8t[p];
    float prod = sL[bl][u] * sL[bl][v];
    float4 w4 = *(const float4*)(wsym + (size_t)p * 128 + w0);
    FMA4(y0acc, w4, prod);
  }
  // ---- y220: flat 256 loop ----
  #pragma unroll 8
  for (int q = 0; q < 256; q++) {
    float gv = grA[bl * 256 + q];
    float4 w4 = *(const float4*)(w220 + (size_t)q * 128 + w0);
    FMA4(y0acc, w4, gv);
  }
  #pragma unroll
  for (int wi = 0; wi < 4; wi++) y0L[bl][w0 + wi] = cf.a0 * y0acc[wi];
  __syncthreads();  // grA dead; union region free for GLb/QLb

  // ---- y2 ----
  float y2acc[5][4];
  #pragma unroll
  for (int k = 0; k < 5; k++)
    #pragma unroll
    for (int wi = 0; wi < 4; wi++) y2acc[k][wi] = 0.f;

  // tp022
  for (int v = 0; v < 16; v++) {
    float a4[4] = {0.f, 0.f, 0.f, 0.f};
    #pragma unroll 8
    for (int u = 0; u < 64; u++) {
      float su = sL[bl][u];
      float4 w4 = *(const float4*)(w022 + (size_t)(u * 16 + v) * 128 + w0);
      FMA4(a4, w4, su);
    }
    #pragma unroll
    for (int k = 0; k < 5; k++) {
      float fk = dk022[k] * tL[bl][v][k];
      #pragma unroll
      for (int wi = 0; wi < 4; wi++) y2acc[k][wi] = fmaf(fk, a4[wi], y2acc[k][wi]);
    }
  }
  // tp202
  for (int u = 0; u < 16; u++) {
    float a4[4] = {0.f, 0.f, 0.f, 0.f};
    #pragma unroll 8
    for (int v = 0; v < 64; v++) {
      float sv = sL[bl][v];
      float4 w4 = *(const float4*)(w202 + (size_t)(u * 64 + v) * 128 + w0);
      FMA4(a4, w4, sv);
    }
    #pragma unroll
    for (int k = 0; k < 5; k++) {
      float fk = dk202[k] * tL[bl][u][k];
      #pragma unroll
      for (int wi = 0; wi < 4; wi++) y2acc[k][wi] = fmaf(fk, a4[wi], y2acc[k][wi]);
    }
  }
  // tp222
  for (int u = 0; u < 16; u++) {
    if (tid < 400) {
      int bb = tid / 25, jk = tid - bb * 25;
      float g = 0.f;
      #pragma unroll
      for (int ii = 0; ii < 5; ii++)
        g = fmaf(cL222[ii * 25 + jk], tL[bb][u][ii], g);
      GLb[bb][jk] = g;
    }
    __syncthreads();
    for (int idx = tid; idx < 1280; idx += 512) {
      int bb = idx / 80, rem = idx - bb * 80;
      int vv = rem / 5, kk = rem - vv * 5;
      float q = 0.f;
      #pragma unroll
      for (int jj = 0; jj < 5; jj++)
        q = fmaf(GLb[bb][jj * 5 + kk], tL[bb][vv][jj], q);
      QLb[bb][vv][kk] = q;
    }
    __syncthreads();
    #pragma unroll 4
    for (int v = 0; v < 16; v++) {
      float4 w4 = *(const float4*)(w222 + (size_t)(u * 16 + v) * 128 + w0);
      #pragma unroll
      for (int k = 0; k < 5; k++) {
        float qv = QLb[bl][v][k];
        FMA4(y2acc[k], w4, qv);
      }
    }
    __syncthreads();   // QLb reads done -> safe to overwrite next iter / y2L
  }
  // store y2 into union region (GLb/QLb dead)
  #pragma unroll
  for (int k = 0; k < 5; k++) {
    float4 o;
    o.x = cf.a2 * y2acc[k][0]; o.y = cf.a2 * y2acc[k][1];
    o.z = cf.a2 * y2acc[k][2]; o.w = cf.a2 * y2acc[k][3];
    *(float4*)(&y2L[bl][k][w0]) = o;
  }
  __syncthreads();

  // ================= phase 5: tp2 (restructured) =================
  const int xv  = tid & 127;
  const int g4  = tid >> 7;     // 4 b's per group
  const int bb5 = tid >> 5;     // reduce-phase b (0..15)
  const int l5  = tid & 31;     // reduce-phase lane

  // ---- 022 path: gv[b][xv] = sum_u W2022[u,xv] y0[b][u] ----
  {
    float acc[4] = {0.f, 0.f, 0.f, 0.f};
    for (int u = 0; u < 128; u += 2) {
      float wa = w2022[(size_t)u * 128 + xv];
      float wb = w2022[(size_t)(u + 1) * 128 + xv];
      #pragma unroll
      for (int r = 0; r < 4; r++) {
        acc[r] = fmaf(wa, y0L[g4 * 4 + r][u], acc[r]);
        acc[r] = fmaf(wb, y0L[g4 * 4 + r][u + 1], acc[r]);
      }
    }
    #pragma unroll
    for (int r = 0; r < 4; r++) gvL[g4 * 4 + r][xv] = acc[r];
  }
  __syncthreads();
  #pragma unroll
  for (int k = 0; k < 5; k++) {
    float p = 0.f;
    #pragma unroll
    for (int j = 0; j < 4; j++)
      p = fmaf(gvL[bb5][l5 + 32 * j], y2L[bb5][k][l5 + 32 * j], p);
    p += __shfl_xor(p, 16); p += __shfl_xor(p, 8); p += __shfl_xor(p, 4);
    p += __shfl_xor(p, 2);  p += __shfl_xor(p, 1);
    if (l5 == 0) corrAcc[bb5][k] = dk022[k] * p;   // first writer: plain store
  }
  __syncthreads();

  // ---- 202 path: hv[b][xv] = sum_v W2202[xv,v] y0[b][v] (via W202T) ----
  {
    float acc[4] = {0.f, 0.f, 0.f, 0.f};
    for (int v = 0; v < 128; v += 2) {
      float wa = w202T[(size_t)v * 128 + xv];
      float wb = w202T[(size_t)(v + 1) * 128 + xv];
      #pragma unroll
      for (int r = 0; r < 4; r++) {
        acc[r] = fmaf(wa, y0L[g4 * 4 + r][v], acc[r]);
        acc[r] = fmaf(wb, y0L[g4 * 4 + r][v + 1], acc[r]);
      }
    }
    __syncthreads();   // prior reduce finished reading gvL
    #pragma unroll
    for (int r = 0; r < 4; r++) gvL[g4 * 4 + r][xv] = acc[r];
  }
  __syncthreads();
  #pragma unroll
  for (int k = 0; k < 5; k++) {
    float p = 0.f;
    #pragma unroll
    for (int j = 0; j < 4; j++)
      p = fmaf(gvL[bb5][l5 + 32 * j], y2L[bb5][k][l5 + 32 * j], p);
    p += __shfl_xor(p, 16); p += __shfl_xor(p, 8); p += __shfl_xor(p, 4);
    p += __shfl_xor(p, 2);  p += __shfl_xor(p, 1);
    if (l5 == 0) corrAcc[bb5][k] += dk202[k] * p;  // same unique writer thread
  }

  // ---- 222 path: Zi[b][xv] = sum_u W2222[u,xv] y2[b][i][u]; P[i][j] ----
  for (int i = 0; i < 5; i++) {
    float acc[4] = {0.f, 0.f, 0.f, 0.f};
    for (int u = 0; u < 128; u += 2) {
      float wa = w2222[(size_t)u * 128 + xv];
      float wb = w2222[(size_t)(u + 1) * 128 + xv];
      #pragma unroll
      for (int r = 0; r < 4; r++) {
        acc[r] = fmaf(wa, y2L[g4 * 4 + r][i][u], acc[r]);
        acc[r] = fmaf(wb, y2L[g4 * 4 + r][i][u + 1], acc[r]);
      }
    }
    __syncthreads();   // prior reduce finished reading gvL
    #pragma unroll
    for (int r = 0; r < 4; r++) gvL[g4 * 4 + r][xv] = acc[r];
    __syncthreads();
    #pragma unroll
    for (int j = 0; j < 5; j++) {
      float p = 0.f;
      #pragma unroll
      for (int jj = 0; jj < 4; jj++)
        p = fmaf(gvL[bb5][l5 + 32 * jj], y2L[bb5][j][l5 + 32 * jj], p);
      p += __shfl_xor(p, 16); p += __shfl_xor(p, 8); p += __shfl_xor(p, 4);
      p += __shfl_xor(p, 2);  p += __shfl_xor(p, 1);
      if (l5 == 0) pPL[bb5][i * 5 + j] = p;        // unique writer
    }
  }
  __syncthreads();

  // ---- epilogue ----
  if (tid < 80) {
    int bb = tid / 5, k = tid - bb * 5;
    float c2 = 0.f;
    #pragma unroll
    for (int ii = 0; ii < 5; ii++)
      #pragma unroll
      for (int jj = 0; jj < 5; jj++)
        c2 = fmaf(cL222[ii * 25 + jj * 5 + k], pPL[bb][ii * 5 + jj], c2);
    float tot = corrAcc[bb][k] + c2;
    int b = b0 + bb;
    out[(size_t)b * 5 + k] = mixed_ws[(size_t)b * 5 + k] + csc[0] * cf.b2 * tot;
  }
}

// ---------------------------------------------------------------------------
// Host: replicate reference's wigner-3j computation (RREF null space).
// ---------------------------------------------------------------------------
namespace {

using cplx = std::complex<double>;

static void su2_gen(int l, std::vector<cplx>& Jx, std::vector<cplx>& Jy,
                    std::vector<cplx>& Jz) {
  int d = 2 * l + 1;
  Jx.assign((size_t)d * d, cplx(0, 0));
  Jy.assign((size_t)d * d, cplx(0, 0));
  Jz.assign((size_t)d * d, cplx(0, 0));
  for (int a = 0; a < d; a++) Jz[(size_t)a * d + a] = cplx(a - l, 0);
  for (int r = 1; r < d; r++) {
    double m = (r - 1) - l;
    double v = std::sqrt(l * (l + 1.0) - m * (m + 1.0));
    Jx[(size_t)r * d + (r - 1)] += cplx(v / 2, 0);
    Jx[(size_t)(r - 1) * d + r] += cplx(v / 2, 0);
    Jy[(size_t)r * d + (r - 1)] += cplx(0, -v / 2);
    Jy[(size_t)(r - 1) * d + r] += cplx(0, v / 2);
  }
}

static void real_basis(int l, std::vector<cplx>& U) {
  int d = 2 * l + 1;
  U.assign((size_t)d * d, cplx(0, 0));
  U[(size_t)l * d + l] = cplx(1, 0);
  double is2 = 1.0 / std::sqrt(2.0);
  for (int m = 1; m <= l; m++) {
    double sgn = (m % 2 == 0) ? 1.0 : -1.0;
    U[(size_t)(l + m) * d + (l + m)] = cplx(sgn * is2, 0);
    U[(size_t)(l + m) * d + (l - m)] = cplx(is2, 0);
    U[(size_t)(l - m) * d + (l - m)] = cplx(0, is2);
    U[(size_t)(l - m) * d + (l + m)] = cplx(0, -sgn * is2);
  }
}

static void real_gens(int l, std::vector<double> G[3]) {
  int d = 2 * l + 1;
  if (l == 0) { for (int a = 0; a < 3; a++) G[a].assign(1, 0.0); return; }
  std::vector<cplx> J[3];
  su2_gen(l, J[0], J[1], J[2]);
  std::vector<cplx> U;
  real_basis(l, U);
  for (int a = 0; a < 3; a++) {
    std::vector<cplx> T((size_t)d * d, cplx(0, 0));
    for (int i = 0; i < d; i++)
      for (int k = 0; k < d; k++) {
        cplx s(0, 0);
        for (int j = 0; j < d; j++)
          s += U[(size_t)i * d + j] * (cplx(0, -1) * J[a][(size_t)j * d + k]);
        T[(size_t)i * d + k] = s;
      }
    G[a].assign((size_t)d * d, 0.0);
    for (int i = 0; i < d; i++)
      for (int k = 0; k < d; k++) {
        cplx s(0, 0);
        for (int j = 0; j < d; j++)
          s += T[(size_t)i * d + j] * std::conj(U[(size_t)k * d + j]);
        G[a][(size_t)i * d + k] = s.real();
      }
  }
}

static void w3j_host(int l1, int l2, int l3, float* out) {
  int d1 = 2 * l1 + 1, d2 = 2 * l2 + 1, d3 = 2 * l3 + 1;
  int D = d1 * d2 * d3;
  std::vector<double> G1[3], G2[3], G3[3];
  real_gens(l1, G1); real_gens(l2, G2); real_gens(l3, G3);
  int R = 3 * D;
  std::vector<double> M((size_t)R * D, 0.0);
  for (int a = 0; a < 3; a++) {
    double* Ma = &M[(size_t)a * D * D];
    for (int i1 = 0; i1 < d1; i1++)
      for (int j1 = 0; j1 < d1; j1++) {
        double g = G1[a][(size_t)i1 * d1 + j1];
        if (g == 0.0) continue;
        for (int i2 = 0; i2 < d2; i2++)
          for (int i3 = 0; i3 < d3; i3++)
            Ma[(size_t)((i1 * d2 + i2) * d3 + i3) * D + ((j1 * d2 + i2) * d3 + i3)] += g;
      }
    for (int i2 = 0; i2 < d2; i2++)
      for (int j2 = 0; j2 < d2; j2++) {
        double g = G2[a][(size_t)i2 * d2 + j2];
        if (g == 0.0) continue;
        for (int i1 = 0; i1 < d1; i1++)
          for (int i3 = 0; i3 < d3; i3++)
            Ma[(size_t)((i1 * d2 + i2) * d3 + i3) * D + ((i1 * d2 + j2) * d3 + i3)] += g;
      }
    for (int i3 = 0; i3 < d3; i3++)
      for (int j3 = 0; j3 < d3; j3++) {
        double g = G3[a][(size_t)i3 * d3 + j3];
        if (g == 0.0) continue;
        for (int i1 = 0; i1 < d1; i1++)
          for (int i2 = 0; i2 < d2; i2++)
            Ma[(size_t)((i1 * d2 + i2) * d3 + i3) * D + ((i1 * d2 + i2) * d3 + j3)] += g;
      }
  }
  std::vector<int> pivcol;
  int rank = 0;
  for (int col = 0; col < D && rank < R; col++) {
    int pr = -1; double pv = 1e-9;
    for (int r = rank; r < R; r++) {
      double av = std::fabs(M[(size_t)r * D + col]);
      if (av > pv) { pv = av; pr = r; }
    }
    if (pr < 0) continue;
    if (pr != rank)
      for (int c = 0; c < D; c++) std::swap(M[(size_t)pr * D + c], M[(size_t)rank * D + c]);
    double inv = 1.0 / M[(size_t)rank * D + col];
    for (int c = 0; c < D; c++) M[(size_t)rank * D + c] *= inv;
    for (int r = 0; r < R; r++) {
      if (r == rank) continue;
      double f = M[(size_t)r * D + col];
      if (f != 0.0)
        for (int c = 0; c < D; c++) M[(size_t)r * D + c] -= f * M[(size_t)rank * D + c];
    }
    pivcol.push_back(col);
    rank++;
  }
  std::vector<char> isp(D, 0);
  for (int c : pivcol) isp[c] = 1;
  int fc = 0;
  for (int c = 0; c < D; c++) if (!isp[c]) { fc = c; break; }
  std::vector<double> x(D, 0.0);
  x[fc] = 1.0;
  for (int r = 0; r < rank; r++) x[pivcol[r]] = -M[(size_t)r * D + fc];
  double n = 0;
  for (double v : x) n += v * v;
  n = std::sqrt(n);
  for (int c = 0; c < D; c++) x[c] /= n;
  double best = 0;
  for (int c = 0; c < D; c++) { double av = std::fabs(x[c]); if (av > best) best = av; }
  double ssum = 0;
  for (int c = 0; c < D; c++) {
    double av = std::fabs(x[c]);
    if (av >= best * 0.999) ssum += (x[c] >= 0 ? 1.0 : -1.0);
  }
  double sgn = (ssum >= 0) ? 1.0 : -1.0;
  for (int c = 0; c < D; c++) out[c] = (float)(x[c] * sgn);
}

}  // namespace

// ---------------------------------------------------------------------------
extern "C" void kernel_launch(void* const* d_in, const int* in_sizes, int n_in,
                              void* d_out, int out_size, void* d_ws, size_t ws_size,
                              hipStream_t stream)
{
  (void)in_sizes; (void)n_in; (void)out_size; (void)ws_size;

  const float* s     = (const float*)d_in[0];
  const float* t2s   = (const float*)d_in[1];
  const float* w1    = (const float*)d_in[2];
  const float* w2    = (const float*)d_in[3];
  const float* w3    = (const float*)d_in[4];
  const float* gthr  = (const float*)d_in[5];
  const float* w000  = (const float*)d_in[6];
  const float* w220  = (const float*)d_in[7];
  const float* w022  = (const float*)d_in[8];
  const float* w202  = (const float*)d_in[9];
  const float* w222  = (const float*)d_in[10];
  const float* w2022 = (const float*)d_in[11];
  const float* w2202 = (const float*)d_in[12];
  const float* w2222 = (const float*)d_in[13];
  const float* csc   = (const float*)d_in[14];
  float* out = (float*)d_out;

  char* ws = (char*)d_ws;
  float* mixed_ws = (float*)(ws + MIX_WS_OFF);
  float* w202T    = (float*)(ws + W202T_OFF);
  float* wsym     = (float*)(ws + WSYM_OFF);

  Coefs cf;
  {
    float c000v[1], c022v[25], c202v[25], c220v[25];
    w3j_host(0, 0, 0, c000v);
    w3j_host(0, 2, 2, c022v);
    w3j_host(2, 0, 2, c202v);
    w3j_host(2, 2, 0, c220v);
    w3j_host(2, 2, 2, cf.c222);
    for (int i = 0; i < 125; i++) cf.c222[i] *= C222_FLIP;
    for (int k = 0; k < 5; k++) {
      cf.d022[k] = c022v[k * 5 + k];
      cf.d202[k] = c202v[k * 5 + k];
      cf.d220[k] = c220v[k * 5 + k];
    }
    (void)c000v;
    cf.a0 = (float)std::sqrt(1.0 / (64.0 * 64.0 + 16.0 * 16.0));
    cf.a2 = (float)std::sqrt(5.0 / (2.0 * 64.0 * 16.0 + 16.0 * 16.0));
    cf.b2 = (float)std::sqrt(5.0 / (3.0 * 128.0 * 128.0));
  }

  hipLaunchKernelGGL(k_prep, dim3(512), dim3(256), 0, stream,
                     s, t2s, w1, w2, w3, gthr, mixed_ws);
  hipLaunchKernelGGL(k_transpose, dim3(64), dim3(256), 0, stream, w2202, w202T);
  hipLaunchKernelGGL(k_symW000, dim3(64), dim3(256), 0, stream, w000, wsym);
  hipLaunchKernelGGL(k_fused, dim3(1024), dim3(512), 0, stream,
                     s, t2s, mixed_ws, wsym, w220, w022, w202, w222,
                     w2022, w202T, w2222, csc, out, cf);
}